// Round 4
// baseline (97.892 us; speedup 1.0000x reference)
//
#include <hip/hip_runtime.h>
#include <math.h>

// B=4096 batches, C=128 classes.
//   p = softmax(mu[b])
//   sigma_y[i,l] = p_i p_l (sigma[i,l] - r[l] - c[i] + s)
//   r = p^T sigma, c = sigma p, s = p^T sigma p
// Streaming memory-bound. Persistent pipelined blocks: grid=256 (1 block/CU,
// 16 waves), NB=16 batches/block, double-buffered register staging so next
// batch's 64KB sigma read is in flight across every barrier. 3 barriers/batch.

#define C_DIM 128
#define TPB   1024
#define F4_PB 4096          // C*C/4 float4 per batch
#define KIT   4             // F4_PB / TPB
#define NB    16            // batches per block

typedef float f4 __attribute__((ext_vector_type(4)));

struct SmemT {
    float c[C_DIM];
    float r[C_DIM];
    float rpart[16][C_DIM];
    float red;
};

__device__ __forceinline__ void issue_batch(
    const f4* __restrict__ sig4, const float* __restrict__ mu,
    size_t bb, int t, int lane, int wave,
    f4 (&v)[KIT], float& x0, float& x1)
{
    const f4* s4 = sig4 + bb * F4_PB;
#pragma unroll
    for (int k = 0; k < KIT; ++k)
        v[k] = __builtin_nontemporal_load(&s4[t + TPB * k]);
    if (wave == 0) {                 // mu prefetch for the softmax wave
        x0 = mu[bb * C_DIM + lane];
        x1 = mu[bb * C_DIM + 64 + lane];
    }
}

__device__ __forceinline__ void process_batch(
    size_t bb, int t, int lane, int wave, int colg, int rowg,
    f4 (&v)[KIT], float x0, float x1,
    float* lds_p,                    // ping-pong slot [128]
    SmemT& sm,
    float* __restrict__ out_p, f4* __restrict__ out_sy)
{
    // ---- Phase A: softmax on wave 0 (2 elems/lane) ----
    if (wave == 0) {
        float m = fmaxf(x0, x1);
#pragma unroll
        for (int off = 32; off >= 1; off >>= 1)
            m = fmaxf(m, __shfl_xor(m, off, 64));
        const float e0 = expf(x0 - m), e1 = expf(x1 - m);
        float ss = e0 + e1;
#pragma unroll
        for (int off = 32; off >= 1; off >>= 1)
            ss += __shfl_xor(ss, off, 64);
        const float inv = 1.0f / ss;
        const float p0 = e0 * inv, p1 = e1 * inv;
        lds_p[lane] = p0;
        lds_p[64 + lane] = p1;
        out_p[bb * C_DIM + lane] = p0;
        out_p[bb * C_DIM + 64 + lane] = p1;
    }
    __syncthreads();                                     // B1

    // ---- Phase B: partial r (p-weighted cols) and c (row dot) ----
    const f4 pcol = *(const f4*)&lds_p[4 * colg];
    f4 pr = (f4)(0.f);
    float pc[KIT];
#pragma unroll
    for (int k = 0; k < KIT; ++k) {
        const float prow = lds_p[rowg + 32 * k];         // half-wave broadcast
        const f4 vk = v[k];
        pr += prow * vk;
        pc[k] = vk.x * pcol.x + vk.y * pcol.y + vk.z * pcol.z + vk.w * pcol.w;
    }
    pr.x += __shfl_xor(pr.x, 32, 64);
    pr.y += __shfl_xor(pr.y, 32, 64);
    pr.z += __shfl_xor(pr.z, 32, 64);
    pr.w += __shfl_xor(pr.w, 32, 64);
    if (lane < 32)
        *(f4*)&sm.rpart[wave][4 * colg] = pr;
#pragma unroll
    for (int off = 1; off <= 16; off <<= 1) {
#pragma unroll
        for (int k = 0; k < KIT; ++k)
            pc[k] += __shfl_xor(pc[k], off, 64);
    }
    if ((lane & 31) == 0) {
#pragma unroll
        for (int k = 0; k < KIT; ++k)
            sm.c[rowg + 32 * k] = pc[k];                 // each row once
    }
    __syncthreads();                                     // B2

    // ---- Phase C: finalize r (waves 0,1); s = p.c (wave 2) ----
    if (t < C_DIM) {
        float rsum = 0.f;
#pragma unroll
        for (int w = 0; w < 16; ++w)
            rsum += sm.rpart[w][t];
        sm.r[t] = rsum;
    }
    if (wave == 2) {
        float sv = lds_p[lane] * sm.c[lane] + lds_p[64 + lane] * sm.c[64 + lane];
#pragma unroll
        for (int off = 32; off >= 1; off >>= 1)
            sv += __shfl_xor(sv, off, 64);
        if (lane == 0) sm.red = sv;
    }
    __syncthreads();                                     // B3

    // ---- Phase D: output (no trailing barrier; lds_p is ping-ponged,
    //      sm.* writes of next batch sit behind next B1/B2) ----
    const f4 r4 = *(const f4*)&sm.r[4 * colg];
    const float s = sm.red;
    f4* o4 = out_sy + bb * F4_PB;
#pragma unroll
    for (int k = 0; k < KIT; ++k) {
        const int row = rowg + 32 * k;
        const float pp   = lds_p[row];
        const float base = s - sm.c[row];
        const f4 vk = v[k];
        f4 o;
        o.x = pp * pcol.x * (vk.x - r4.x + base);
        o.y = pp * pcol.y * (vk.y - r4.y + base);
        o.z = pp * pcol.z * (vk.z - r4.z + base);
        o.w = pp * pcol.w * (vk.w - r4.w + base);
        __builtin_nontemporal_store(o, &o4[t + TPB * k]);
    }
}

__global__ __launch_bounds__(TPB, 4) void vdp_softmax_kernel(
    const float* __restrict__ mu,
    const float* __restrict__ sigma,
    float* __restrict__ out_p,
    float* __restrict__ out_sy)
{
    const int t    = threadIdx.x;
    const int lane = t & 63;
    const int wave = t >> 6;    // 0..15
    const int colg = t & 31;    // columns 4*colg .. 4*colg+3
    const int rowg = t >> 5;    // 0..31; rows rowg + 32k

    __shared__ SmemT sm;
    __shared__ float lds_p2[2][C_DIM];   // ping-pong p buffer

    const size_t b0 = (size_t)blockIdx.x * NB;
    const f4* sig4 = (const f4*)sigma;
    f4* o4 = (f4*)out_sy;

    f4 vA[KIT], vB[KIT];
    float xA0 = 0.f, xA1 = 0.f, xB0 = 0.f, xB1 = 0.f;

    issue_batch(sig4, mu, b0, t, lane, wave, vA, xA0, xA1);

#pragma unroll 1
    for (int it = 0; it < NB; it += 2) {
        // loads for batch it+1 in flight during all of batch it
        issue_batch(sig4, mu, b0 + it + 1, t, lane, wave, vB, xB0, xB1);
        process_batch(b0 + it, t, lane, wave, colg, rowg,
                      vA, xA0, xA1, lds_p2[0], sm, out_p, o4);
        if (it + 2 < NB)
            issue_batch(sig4, mu, b0 + it + 2, t, lane, wave, vA, xA0, xA1);
        process_batch(b0 + it + 1, t, lane, wave, colg, rowg,
                      vB, xB0, xB1, lds_p2[1], sm, out_p, o4);
    }
}

extern "C" void kernel_launch(void* const* d_in, const int* in_sizes, int n_in,
                              void* d_out, int out_size, void* d_ws, size_t ws_size,
                              hipStream_t stream) {
    const float* mu    = (const float*)d_in[0];
    const float* sigma = (const float*)d_in[1];
    float* out_p  = (float*)d_out;                  // [B, C]
    const int B = in_sizes[0] / C_DIM;              // 4096
    float* out_sy = out_p + (size_t)B * C_DIM;      // [B, C, C]

    vdp_softmax_kernel<<<B / NB, TPB, 0, stream>>>(mu, sigma, out_p, out_sy);
}

// Round 5
// 93.311 us; speedup vs baseline: 1.0491x; 1.0491x over previous
//
#include <hip/hip_runtime.h>
#include <math.h>

// B=4096 batches, C=128 classes.
//   p = softmax(mu[b])
//   sigma_y[i,l] = p_i p_l (sigma[i,l] - r[l] - c[i] + s)
//   r = p^T sigma, c = sigma p, s = p^T sigma p
// Streaming memory-bound: sigma read once, sigma_y written once.
// Round-2 structure (grid=4096, TPB=1024, <=64 VGPR -> 2 blocks/CU for
// inter-block overlap) + round-3's single-wave softmax (3 barriers, not 5).

#define C_DIM   128
#define TPB     1024
#define F4_PB   4096        // C*C/4 float4 per batch
#define KIT     4           // F4_PB / TPB

typedef float f4 __attribute__((ext_vector_type(4)));

__global__ __launch_bounds__(TPB, 8) void vdp_softmax_kernel(
    const float* __restrict__ mu,
    const float* __restrict__ sigma,
    float* __restrict__ out_p,
    float* __restrict__ out_sy)
{
    const int b    = blockIdx.x;
    const int t    = threadIdx.x;
    const int lane = t & 63;
    const int wave = t >> 6;    // 0..15
    const int colg = t & 31;    // columns 4*colg .. 4*colg+3
    const int rowg = t >> 5;    // 0..31; rows rowg + 32k, k=0..3

    __shared__ float lds_p[C_DIM];
    __shared__ float lds_c[C_DIM];
    __shared__ float lds_r[C_DIM];
    __shared__ float lds_rpart[16][C_DIM];
    __shared__ float lds_red;

    // ---- issue all sigma loads early (independent of softmax) ----
    const f4* sig4 = (const f4*)sigma + (size_t)b * F4_PB;
    f4 v[KIT];
#pragma unroll
    for (int k = 0; k < KIT; ++k)
        v[k] = __builtin_nontemporal_load(&sig4[t + TPB * k]);

    // ---- softmax on wave 0 only: 2 elems/lane, shuffle-only ----
    if (wave == 0) {
        const float x0 = mu[(size_t)b * C_DIM + lane];
        const float x1 = mu[(size_t)b * C_DIM + 64 + lane];
        float m = fmaxf(x0, x1);
#pragma unroll
        for (int off = 32; off >= 1; off >>= 1)
            m = fmaxf(m, __shfl_xor(m, off, 64));
        const float e0 = expf(x0 - m), e1 = expf(x1 - m);
        float ss = e0 + e1;
#pragma unroll
        for (int off = 32; off >= 1; off >>= 1)
            ss += __shfl_xor(ss, off, 64);
        const float inv = 1.0f / ss;
        const float p0 = e0 * inv, p1 = e1 * inv;
        lds_p[lane] = p0;
        lds_p[64 + lane] = p1;
        out_p[(size_t)b * C_DIM + lane] = p0;
        out_p[(size_t)b * C_DIM + 64 + lane] = p1;
    }
    __syncthreads();                                     // B1: p visible

    // ---- partial r (per-column, p-weighted) and c (per-row dot) ----
    const f4 pcol = *(const f4*)&lds_p[4 * colg];
    f4 pr = (f4)(0.f);
    float pc[KIT];
#pragma unroll
    for (int k = 0; k < KIT; ++k) {
        const float prow = lds_p[rowg + 32 * k];   // broadcast per half-wave
        const f4 vk = v[k];
        pr += prow * vk;
        pc[k] = vk.x * pcol.x + vk.y * pcol.y + vk.z * pcol.z + vk.w * pcol.w;
    }

    // r: lanes l and l+32 share colg -> combine, then 16 wave partials
    pr.x += __shfl_xor(pr.x, 32, 64);
    pr.y += __shfl_xor(pr.y, 32, 64);
    pr.z += __shfl_xor(pr.z, 32, 64);
    pr.w += __shfl_xor(pr.w, 32, 64);
    if (lane < 32)
        *(f4*)&lds_rpart[wave][4 * colg] = pr;

    // c: each half-wave owns one rowg; reduce its 32 column groups
#pragma unroll
    for (int off = 1; off <= 16; off <<= 1) {
#pragma unroll
        for (int k = 0; k < KIT; ++k)
            pc[k] += __shfl_xor(pc[k], off, 64);
    }
    if ((lane & 31) == 0) {
#pragma unroll
        for (int k = 0; k < KIT; ++k)
            lds_c[rowg + 32 * k] = pc[k];          // each row written once
    }
    __syncthreads();                                     // B2: rpart, c visible

    // ---- finalize r (128 threads); s = p.c (wave 2) ----
    if (t < C_DIM) {
        float rsum = 0.f;
#pragma unroll
        for (int w = 0; w < 16; ++w)
            rsum += lds_rpart[w][t];
        lds_r[t] = rsum;
    }
    if (wave == 2) {
        float sv = lds_p[lane] * lds_c[lane] + lds_p[64 + lane] * lds_c[64 + lane];
#pragma unroll
        for (int off = 32; off >= 1; off >>= 1)
            sv += __shfl_xor(sv, off, 64);
        if (lane == 0) lds_red = sv;
    }
    __syncthreads();                                     // B3: r, s visible

    // ---- output ----
    const f4 r4 = *(const f4*)&lds_r[4 * colg];
    const float s = lds_red;
    f4* out4 = (f4*)out_sy + (size_t)b * F4_PB;
#pragma unroll
    for (int k = 0; k < KIT; ++k) {
        const int row = rowg + 32 * k;
        const float pp   = lds_p[row];
        const float base = s - lds_c[row];
        const f4 vk = v[k];
        f4 o;
        o.x = pp * pcol.x * (vk.x - r4.x + base);
        o.y = pp * pcol.y * (vk.y - r4.y + base);
        o.z = pp * pcol.z * (vk.z - r4.z + base);
        o.w = pp * pcol.w * (vk.w - r4.w + base);
        __builtin_nontemporal_store(o, &out4[t + TPB * k]);
    }
}

extern "C" void kernel_launch(void* const* d_in, const int* in_sizes, int n_in,
                              void* d_out, int out_size, void* d_ws, size_t ws_size,
                              hipStream_t stream) {
    const float* mu    = (const float*)d_in[0];
    const float* sigma = (const float*)d_in[1];
    float* out_p  = (float*)d_out;                  // [B, C]
    const int B = in_sizes[0] / C_DIM;              // 4096
    float* out_sy = out_p + (size_t)B * C_DIM;      // [B, C, C]

    vdp_softmax_kernel<<<B, TPB, 0, stream>>>(mu, sigma, out_p, out_sy);
}